// Round 19
// baseline (405.047 us; speedup 1.0000x reference)
//
#include <hip/hip_runtime.h>
#include <math.h>

#define NSEQ 32768

using short8v = __attribute__((ext_vector_type(8))) short;
using f32x4   = __attribute__((ext_vector_type(4))) float;
#define MFMA16 __builtin_amdgcn_mfma_f32_16x16x32_bf16

__device__ __forceinline__ unsigned short f2bf(float f){
  union{float f; unsigned u;} v; v.f = f;
  return (unsigned short)((v.u + 0x7FFFu + ((v.u>>16)&1u))>>16);
}
__device__ __forceinline__ float bf2f(unsigned short h){
  union{unsigned u; float f;} v; v.u = ((unsigned)h)<<16; return v.f;
}
__device__ __forceinline__ void split2(float f, unsigned short* h, unsigned short* l){
  unsigned short hh = f2bf(f);
  *h = hh; *l = f2bf(f - bf2f(hh));
}
// pack hi(rounded bf16) | lo-bf16(truncated)<<16 ; value = hi + lo
__device__ __forceinline__ unsigned pack2(float f){
  unsigned short hh = f2bf(f);
  union{float f; unsigned u;} rv; rv.f = f - bf2f(hh);
  return (unsigned)hh | (rv.u & 0xFFFF0000u);
}
__device__ __forceinline__ float gelu_f(float x){
  return 0.5f*x*(1.f + erff(x*0.70710678118654752f));
}

// ---------------------------------------------------------------------------
// K0: Wx [256][512] fp32 -> WxTH/WxTL [512][256] split-bf16 (transposed). Once.
// ---------------------------------------------------------------------------
__global__ __launch_bounds__(256) void k0_prep(const float* __restrict__ Wx,
    unsigned short* __restrict__ WxTH, unsigned short* __restrict__ WxTL)
{
  const int n = blockIdx.x;
  const int k = threadIdx.x;
  float v = Wx[(size_t)k*512 + n];
  unsigned short hh, ll; split2(v,&hh,&ll);
  WxTH[n*256+k]=hh; WxTL[n*256+k]=ll;
}

// ---------------------------------------------------------------------------
// K0b: prep all small weights as transposed split-bf16. grid 11 x 256.
// ---------------------------------------------------------------------------
__global__ __launch_bounds__(256) void k0b_prep(
  const float* __restrict__ Wq, const float* __restrict__ Wk, const float* __restrict__ Wv,
  const float* __restrict__ Wg1, const float* __restrict__ Wg2, const float* __restrict__ Wo,
  const float* __restrict__ W1, const float* __restrict__ Ws,
  unsigned short* __restrict__ WqTH, unsigned short* __restrict__ WqTL,
  unsigned short* __restrict__ WkTH, unsigned short* __restrict__ WkTL,
  unsigned short* __restrict__ WvTH, unsigned short* __restrict__ WvTL,
  unsigned short* __restrict__ Wg1TH, unsigned short* __restrict__ Wg1TL,
  unsigned short* __restrict__ Wg2TH, unsigned short* __restrict__ Wg2TL,
  unsigned short* __restrict__ WoTH, unsigned short* __restrict__ WoTL,
  unsigned short* __restrict__ W1TH, unsigned short* __restrict__ W1TL,
  unsigned short* __restrict__ WsTH, unsigned short* __restrict__ WsTL)
{
  const int bx = blockIdx.x, t = threadIdx.x;
  unsigned short hh, ll;
  if (bx == 0){
    for (int i=0;i<16;i++){ int idx=i*256+t; int r=idx>>6, c=idx&63;
      split2(Wq[r*64+c],&hh,&ll); WqTH[c*64+r]=hh; WqTL[c*64+r]=ll;
      split2(Wk[r*64+c],&hh,&ll); WkTH[c*64+r]=hh; WkTL[c*64+r]=ll;
      split2(Wv[r*64+c],&hh,&ll); WvTH[c*64+r]=hh; WvTL[c*64+r]=ll;
    }
  } else if (bx == 1){
    for (int i=0;i<32;i++){ int idx=i*256+t; int r=idx>>6, c=idx&63;
      split2(Wg1[r*64+c],&hh,&ll); Wg1TH[c*128+r]=hh; Wg1TL[c*128+r]=ll;
    }
  } else if (bx == 2){
    for (int i=0;i<16;i++){ int idx=i*256+t; int r=idx>>6, c=idx&63;
      split2(Wg2[r*64+c],&hh,&ll); Wg2TH[c*64+r]=hh; Wg2TL[c*64+r]=ll;
      split2(W1[r*64+c],&hh,&ll);  W1TH[c*64+r]=hh;  W1TL[c*64+r]=ll;
      split2(Ws[r*64+c],&hh,&ll);  WsTH[c*64+r]=hh;  WsTL[c*64+r]=ll;
    }
  } else {
    int kb = (bx-3)*64;
    for (int i=0;i<64;i++){ int k = kb+i;
      split2(Wo[(size_t)k*256 + t],&hh,&ll);
      WoTH[(size_t)t*512 + k]=hh; WoTL[(size_t)t*512 + k]=ll;
    }
  }
}

// ---------------------------------------------------------------------------
// K1 v4: same as v3 but stores xmid PACKED (hi|lo<<16, 4B/elem).
// ---------------------------------------------------------------------------
__global__ __launch_bounds__(256,2) void k1_gemm_rope(
    const float* __restrict__ x, const float* __restrict__ pos,
    const unsigned short* __restrict__ WxTH, const unsigned short* __restrict__ WxTL,
    const float* __restrict__ bx,
    const float* __restrict__ Wr, const float* __restrict__ br,
    unsigned* __restrict__ xmidP)
{
  __shared__ unsigned short SA[2*64*128];
  __shared__ unsigned short SB[2*64*128];
  __shared__ float trig[64][8];
  const int tid = threadIdx.x;
  const int wave = tid>>6, lane = tid&63, l15 = lane&15, lq = lane>>4;
  const int m0 = blockIdx.x*64;

  if (tid < 64){
    int m = m0 + tid;
    float a0 = pos[m*3+0];
    float a1 = pos[m*3+1] * 0.046415888336127774f;
    float a2 = pos[m*3+2] * 0.002154434690031884f;
    trig[tid][0]=sinf(a0); trig[tid][1]=sinf(a1); trig[tid][2]=sinf(a2);
    trig[tid][3]=cosf(a0); trig[tid][4]=cosf(a1); trig[tid][5]=cosf(a2);
  }

  short8v aHr[8], aLr[8];
  {
    const int lm = tid>>2, lkq = (tid&3)*32;
    #pragma unroll
    for (int kh=0; kh<2; kh++){
      __syncthreads();
      const float* src = x + (size_t)(m0+lm)*256 + kh*128 + lkq;
      #pragma unroll
      for (int i=0;i<8;i++){
        float4 v = *(const float4*)(src + i*4);
        ushort4 hh, ll;
        split2(v.x,&hh.x,&ll.x); split2(v.y,&hh.y,&ll.y);
        split2(v.z,&hh.z,&ll.z); split2(v.w,&hh.w,&ll.w);
        int G = (lkq>>3) + (i>>1);
        int idx = lm*128 + (((G ^ (lm&15)))<<3) + ((i&1)<<2);
        *(ushort4*)&SA[idx] = hh;
        *(ushort4*)&SA[64*128 + idx] = ll;
      }
      __syncthreads();
      const int row = wave*16 + l15;
      #pragma unroll
      for (int ks=0; ks<4; ks++){
        int idx = row*128 + ((((ks<<2)+lq) ^ l15)<<3);
        aHr[kh*4+ks] = *(const short8v*)&SA[idx];
        aLr[kh*4+ks] = *(const short8v*)&SA[64*128 + idx];
      }
    }
  }

  float ropev[4][4];
  #pragma unroll
  for (int r=0;r<4;r++){
    int tk = wave*16 + lq*4 + r;
    float t0=trig[tk][0],t1=trig[tk][1],t2=trig[tk][2];
    float t3=trig[tk][3],t4=trig[tk][4],t5=trig[tk][5];
    #pragma unroll
    for (int j=0;j<4;j++){
      int d = j*16 + l15;
      float v = br[d];
      v = fmaf(t0, Wr[0*64+d], v);
      v = fmaf(t1, Wr[1*64+d], v);
      v = fmaf(t2, Wr[2*64+d], v);
      v = fmaf(t3, Wr[3*64+d], v);
      v = fmaf(t4, Wr[4*64+d], v);
      v = fmaf(t5, Wr[5*64+d], v);
      ropev[r][j] = v;
    }
  }

  const int bidx = m0 >> 15;
  const int nbase = (m0 & 32767) + wave*16 + lq*4;
  const int ln = tid>>2, lnkq = (tid&3)*32;

  for (int h=0; h<8; h++){
    f32x4 acc[4] = {};
    #pragma unroll
    for (int kh=0; kh<2; kh++){
      __syncthreads();
      {
        const unsigned short* sH = WxTH + (size_t)(h*64+ln)*256 + kh*128 + lnkq;
        const unsigned short* sL = WxTL + (size_t)(h*64+ln)*256 + kh*128 + lnkq;
        int g0 = lnkq>>3;
        #pragma unroll
        for (int i=0;i<4;i++){
          int idx = ln*128 + (((g0+i) ^ (ln&15))<<3);
          *(uint4*)&SB[idx]          = *(const uint4*)(sH + i*8);
          *(uint4*)&SB[64*128 + idx] = *(const uint4*)(sL + i*8);
        }
      }
      __syncthreads();
      #pragma unroll
      for (int ks=0; ks<4; ks++){
        short8v a_h = aHr[kh*4+ks], a_l = aLr[kh*4+ks];
        #pragma unroll
        for (int j=0;j<4;j++){
          int idx = (j*16+l15)*128 + ((((ks<<2)+lq) ^ l15)<<3);
          short8v b_h = *(const short8v*)&SB[idx];
          short8v b_l = *(const short8v*)&SB[64*128 + idx];
          acc[j] = MFMA16(a_h,b_h,acc[j],0,0,0);
          acc[j] = MFMA16(a_h,b_l,acc[j],0,0,0);
          acc[j] = MFMA16(a_l,b_h,acc[j],0,0,0);
        }
      }
    }
    #pragma unroll
    for (int j=0;j<4;j++){
      int col = j*16 + l15;
      float bxv = bx[h*64+col];
      #pragma unroll
      for (int r=0;r<4;r++){
        xmidP[(((size_t)(bidx*8+h))*NSEQ + nbase + r)*64 + col] =
          pack2(acc[j][r] + bxv + ropev[r][j]);
      }
    }
  }
}

// ---------------------------------------------------------------------------
// K2 v8: v7 structure, xmid packed -> XB stage and xf frags are bit-extract
// (no split2 on the xmid read paths).
// ---------------------------------------------------------------------------
__global__ __launch_bounds__(256,2) void k2_tile(
  const unsigned* __restrict__ xmidP, const float* __restrict__ gum,
  const unsigned short* __restrict__ W1TH, const unsigned short* __restrict__ W1TL,
  const float* __restrict__ b1,
  const float* __restrict__ W2, const float* __restrict__ b2,
  const float* __restrict__ biasp,
  const unsigned short* __restrict__ WsTH, const unsigned short* __restrict__ WsTL,
  const float* __restrict__ bs,
  unsigned* __restrict__ swT, float* __restrict__ part)
{
  __shared__ unsigned short XBh[64*72], XBl[64*72];
  __shared__ unsigned short W1h[64*72], W1l[64*72];
  __shared__ unsigned short Wsh[64*72], Wsl[64*72];
  __shared__ unsigned short swh[64*72], swl[64*72];
  __shared__ float snred[4*64];
  __shared__ float prm[200];

  const int tid = threadIdx.x;
  const int wave = tid>>6, lane = tid&63, l15 = lane&15, lq = lane>>4;
  const int bh = blockIdx.y, chunk = blockIdx.x, h = bh&7;
  const size_t rowbase = (size_t)bh*NSEQ;

  {
    const int g = tid>>2, c16 = (tid&3)*16;
    *(uint4*)&W1h[g*72+c16]   = *(const uint4*)(W1TH + g*64 + c16);
    *(uint4*)&W1h[g*72+c16+8] = *(const uint4*)(W1TH + g*64 + c16 + 8);
    *(uint4*)&W1l[g*72+c16]   = *(const uint4*)(W1TL + g*64 + c16);
    *(uint4*)&W1l[g*72+c16+8] = *(const uint4*)(W1TL + g*64 + c16 + 8);
    *(uint4*)&Wsh[g*72+c16]   = *(const uint4*)(WsTH + g*64 + c16);
    *(uint4*)&Wsh[g*72+c16+8] = *(const uint4*)(WsTH + g*64 + c16 + 8);
    *(uint4*)&Wsl[g*72+c16]   = *(const uint4*)(WsTL + g*64 + c16);
    *(uint4*)&Wsl[g*72+c16+8] = *(const uint4*)(WsTL + g*64 + c16 + 8);
  }
  if (tid<64){ prm[tid]=b1[tid]; prm[64+tid]=bs[tid]; prm[128+tid]=W2[tid]; }
  if (tid==64){ prm[192]=b2[0]; prm[193]=biasp[h]; }
  __syncthreads();

  f32x4 acc2[4] = {};
  float snacc[4][4] = {};
  const int mloc = wave*16 + l15;
  const int mq = (tid>>4)*4, dq = (tid&15)*4;

  for (int sub=0; sub<8; ++sub){
    const int n0 = chunk*512 + sub*64;

    { // PRODUCE 1: stage XB [d][m] via bit-extract 4x4 transpose
      const unsigned* src = xmidP + (rowbase + n0 + mq)*64 + dq;
      unsigned pv[4][4];
      #pragma unroll
      for (int i=0;i<4;i++){
        uint4 v = *(const uint4*)(src + (size_t)i*64);
        pv[i][0]=v.x; pv[i][1]=v.y; pv[i][2]=v.z; pv[i][3]=v.w;
      }
      #pragma unroll
      for (int j=0;j<4;j++){
        int d = dq+j;
        ushort4 th, tl;
        th.x=(unsigned short)(pv[0][j]&0xFFFFu); tl.x=(unsigned short)(pv[0][j]>>16);
        th.y=(unsigned short)(pv[1][j]&0xFFFFu); tl.y=(unsigned short)(pv[1][j]>>16);
        th.z=(unsigned short)(pv[2][j]&0xFFFFu); tl.z=(unsigned short)(pv[2][j]>>16);
        th.w=(unsigned short)(pv[3][j]&0xFFFFu); tl.w=(unsigned short)(pv[3][j]>>16);
        *(ushort4*)&XBh[d*72 + mq] = th;
        *(ushort4*)&XBl[d*72 + mq] = tl;
      }
    }

    // PRODUCE 2: per-lane frag loads (packed) + GEMM1 + gumbel -> sw LDS
    uint4 xfp[4];
    {
      const unsigned* xrow = xmidP + (rowbase + n0 + mloc)*64;
      #pragma unroll
      for (int ks=0; ks<2; ks++){
        const int koff = ks*32 + lq*8;
        xfp[ks*2]   = *(const uint4*)(xrow + koff);
        xfp[ks*2+1] = *(const uint4*)(xrow + koff + 4);
      }
    }
    const float* grow = gum + (rowbase + n0 + mloc)*64;
    float4 gu[4];
    #pragma unroll
    for (int gt=0; gt<4; gt++) gu[gt] = *(const float4*)(grow + gt*16 + lq*4);

    f32x4 t1a[4] = {}, lga[4] = {};
    #pragma unroll
    for (int ks=0; ks<2; ks++){
      const int koff = ks*32 + lq*8;
      unsigned pp[8] = {xfp[ks*2].x,xfp[ks*2].y,xfp[ks*2].z,xfp[ks*2].w,
                        xfp[ks*2+1].x,xfp[ks*2+1].y,xfp[ks*2+1].z,xfp[ks*2+1].w};
      short8v xH, xL;
      #pragma unroll
      for (int j=0;j<8;j++){
        xH[j] = (short)(pp[j]&0xFFFFu);
        xL[j] = (short)(pp[j]>>16);
      }
      #pragma unroll
      for (int gt=0; gt<4; gt++){
        const int aoff = (gt*16+l15)*72 + koff;
        short8v wH = *(const short8v*)&W1h[aoff];
        short8v wL = *(const short8v*)&W1l[aoff];
        t1a[gt] = MFMA16(wH,xH,t1a[gt],0,0,0);
        t1a[gt] = MFMA16(wH,xL,t1a[gt],0,0,0);
        t1a[gt] = MFMA16(wL,xH,t1a[gt],0,0,0);
        short8v sH = *(const short8v*)&Wsh[aoff];
        short8v sL = *(const short8v*)&Wsl[aoff];
        lga[gt] = MFMA16(sH,xH,lga[gt],0,0,0);
        lga[gt] = MFMA16(sH,xL,lga[gt],0,0,0);
        lga[gt] = MFMA16(sL,xH,lga[gt],0,0,0);
      }
    }

    float p = 0.f;
    #pragma unroll
    for (int gt=0; gt<4; gt++)
      #pragma unroll
      for (int r=0;r<4;r++){
        int g = gt*16 + lq*4 + r;
        p += gelu_f(t1a[gt][r] + prm[g]) * prm[128+g];
      }
    p += __shfl_xor(p,16); p += __shfl_xor(p,32);
    float t2 = gelu_f(p + prm[192]);
    float rtemp = 1.f / fmaxf(t2 + prm[193], 0.01f);

    float z[4][4]; float mx = -1e30f;
    #pragma unroll
    for (int gt=0; gt<4; gt++){
      float guv[4] = {gu[gt].x, gu[gt].y, gu[gt].z, gu[gt].w};
      #pragma unroll
      for (int r=0;r<4;r++){
        int g = gt*16 + lq*4 + r;
        float gn = -__logf(-__logf(guv[r]+1e-8f)+1e-8f);
        float zz = (lga[gt][r] + prm[64+g] + gn)*rtemp;
        z[gt][r]=zz; mx = fmaxf(mx, zz);
      }
    }
    mx = fmaxf(mx, __shfl_xor(mx,16)); mx = fmaxf(mx, __shfl_xor(mx,32));
    float se = 0.f;
    #pragma unroll
    for (int gt=0; gt<4; gt++)
      #pragma unroll
      for (int r=0;r<4;r++){ float e = __expf(z[gt][r]-mx); z[gt][r]=e; se += e; }
    se += __shfl_xor(se,16); se += __shfl_xor(se,32);
    float inv = 1.f/se;
    #pragma unroll
    for (int gt=0; gt<4; gt++)
      #pragma unroll
      for (int r=0;r<4;r++){
        float swv = z[gt][r]*inv;
        snacc[gt][r] += swv;
        int g = gt*16 + lq*4 + r;
        unsigned short hh,ll; split2(swv,&hh,&ll);
        swh[g*72 + mloc] = hh; swl[g*72 + mloc] = ll;
      }

    __syncthreads();   // A

    {
      const int g = tid>>2, mq2 = (tid&3)*16;
      #pragma unroll
      for (int i=0;i<4;i++){
        ushort4 hh = *(const ushort4*)&swh[g*72 + mq2 + i*4];
        ushort4 ll = *(const ushort4*)&swl[g*72 + mq2 + i*4];
        uint4 pk;
        pk.x = (unsigned)hh.x | ((unsigned)ll.x<<16);
        pk.y = (unsigned)hh.y | ((unsigned)ll.y<<16);
        pk.z = (unsigned)hh.z | ((unsigned)ll.z<<16);
        pk.w = (unsigned)hh.w | ((unsigned)ll.w<<16);
        *(uint4*)(swT + ((size_t)bh*64 + g)*NSEQ + n0 + mq2 + i*4) = pk;
      }
    }

    #pragma unroll
    for (int ks=0; ks<2; ks++){
      const int koff = ks*32 + lq*8;
      short8v aH = *(const short8v*)&swh[(wave*16+l15)*72 + koff];
      short8v aL = *(const short8v*)&swl[(wave*16+l15)*72 + koff];
      #pragma unroll
      for (int dt=0; dt<4; dt++){
        const int d = dt*16 + l15;
        short8v bH = *(const short8v*)&XBh[d*72 + koff];
        short8v bL = *(const short8v*)&XBl[d*72 + koff];
        acc2[dt] = MFMA16(aH,bH,acc2[dt],0,0,0);
        acc2[dt] = MFMA16(aH,bL,acc2[dt],0,0,0);
        acc2[dt] = MFMA16(aL,bH,acc2[dt],0,0,0);
      }
    }

    __syncthreads();   // B
  }

  float* pb = part + ((size_t)bh*64 + chunk)*4160;
  #pragma unroll
  for (int dt=0; dt<4; dt++)
    #pragma unroll
    for (int r=0;r<4;r++){
      int g = wave*16 + lq*4 + r;
      int d = dt*16 + l15;
      pb[g*64 + d] = acc2[dt][r];
    }
  #pragma unroll
  for (int gt=0; gt<4; gt++)
    #pragma unroll
    for (int r=0;r<4;r++){
      float v = snacc[gt][r];
      v += __shfl_xor(v,1); v += __shfl_xor(v,2);
      v += __shfl_xor(v,4); v += __shfl_xor(v,8);
      if (l15==0) snred[wave*64 + gt*16 + lq*4 + r] = v;
    }
  __syncthreads();
  if (tid < 64){
    float s = 0.f;
    #pragma unroll
    for (int w=0; w<4; w++) s += snred[w*64 + tid];
    pb[4096 + tid] = s;
  }
}

// ---------------------------------------------------------------------------
// K3a: reduce 64 chunk-partials -> stred[bh][4160]. grid (16, 17)
// ---------------------------------------------------------------------------
__global__ __launch_bounds__(256) void k3a_reduce(
    const float* __restrict__ part, float* __restrict__ stred)
{
  const int bh = blockIdx.x;
  const int i = blockIdx.y*256 + threadIdx.x;
  if (i >= 4160) return;
  const float* pb = part + (size_t)bh*64*4160 + i;
  float s[8] = {};
  #pragma unroll 2
  for (int c=0; c<64; c+=8)
    #pragma unroll
    for (int j=0;j<8;j++) s[j] += pb[(size_t)(c+j)*4160];
  stred[bh*4160 + i] = ((s[0]+s[1])+(s[2]+s[3])) + ((s[4]+s[5])+(s[6]+s[7]));
}

// ---------------------------------------------------------------------------
// K3b: per (b,h), 4 waves, all matmuls split-bf16 MFMA. Mt written PACKED.
// ---------------------------------------------------------------------------
__global__ __launch_bounds__(256) void k3b_slice(
    const float* __restrict__ stred,
    const unsigned short* __restrict__ WqTH, const unsigned short* __restrict__ WqTL,
    const unsigned short* __restrict__ WkTH, const unsigned short* __restrict__ WkTL,
    const unsigned short* __restrict__ WvTH, const unsigned short* __restrict__ WvTL,
    const unsigned short* __restrict__ Wg1TH, const unsigned short* __restrict__ Wg1TL,
    const unsigned short* __restrict__ Wg2TH, const unsigned short* __restrict__ Wg2TL,
    const unsigned short* __restrict__ WoTH, const unsigned short* __restrict__ WoTL,
    const float* __restrict__ bg1, const float* __restrict__ bg2,
    unsigned* __restrict__ MtP)
{
  __shared__ unsigned short stH[64*72], stL[64*72];
  __shared__ unsigned short qH[64*72],  qL[64*72];
  __shared__ unsigned short kH[64*72],  kL[64*72];
  __shared__ unsigned short vTH[64*72], vTL[64*72];
  __shared__ unsigned short pH[64*72],  pL[64*72];
  __shared__ unsigned short oH[64*72],  oL[64*72];
  __shared__ unsigned short h1H[64*72], h1L[64*72];
  __shared__ unsigned short gH[64*72],  gL[64*72];
  __shared__ float snl[64];

  const int tid = threadIdx.x;
  const int wave = tid>>6, lane = tid&63, l15 = lane&15, lq = lane>>4;
  const int bh = blockIdx.x, h = bh&7;
  const int grow = wave*16 + lq*4;

  if (tid < 64) snl[tid] = stred[bh*4160 + 4096 + tid] + 1e-5f;
  __syncthreads();
  {
    const int g = tid>>2, doff = (tid&3)*16;
    const float sn = snl[g];
    #pragma unroll
    for (int i=0;i<4;i++){
      float4 v = *(const float4*)(stred + bh*4160 + g*64 + doff + i*4);
      ushort4 hh, ll;
      split2(v.x/sn,&hh.x,&ll.x); split2(v.y/sn,&hh.y,&ll.y);
      split2(v.z/sn,&hh.z,&ll.z); split2(v.w/sn,&hh.w,&ll.w);
      *(ushort4*)&stH[g*72 + doff + i*4] = hh;
      *(ushort4*)&stL[g*72 + doff + i*4] = ll;
    }
  }
  __syncthreads();

  // QKV
  {
    f32x4 aq[4]={}, ak[4]={}, av[4]={};
    #pragma unroll
    for (int ks=0; ks<2; ks++){
      const int koff = ks*32 + lq*8;
      short8v sH = *(const short8v*)&stH[(wave*16+l15)*72 + koff];
      short8v sL = *(const short8v*)&stL[(wave*16+l15)*72 + koff];
      #pragma unroll
      for (int j=0;j<4;j++){
        const int boff = (j*16+l15)*64 + koff;
        short8v bH, bL;
        bH = *(const short8v*)(WqTH+boff); bL = *(const short8v*)(WqTL+boff);
        aq[j]=MFMA16(sH,bH,aq[j],0,0,0); aq[j]=MFMA16(sH,bL,aq[j],0,0,0); aq[j]=MFMA16(sL,bH,aq[j],0,0,0);
        bH = *(const short8v*)(WkTH+boff); bL = *(const short8v*)(WkTL+boff);
        ak[j]=MFMA16(sH,bH,ak[j],0,0,0); ak[j]=MFMA16(sH,bL,ak[j],0,0,0); ak[j]=MFMA16(sL,bH,ak[j],0,0,0);
        bH = *(const short8v*)(WvTH+boff); bL = *(const short8v*)(WvTL+boff);
        av[j]=MFMA16(sH,bH,av[j],0,0,0); av[j]=MFMA16(sH,bL,av[j],0,0,0); av[j]=MFMA16(sL,bH,av[j],0,0,0);
      }
    }
    #pragma unroll
    for (int j=0;j<4;j++){
      #pragma unroll
      for (int r=0;r<4;r++){
        unsigned short hh,ll;
        split2(aq[j][r],&hh,&ll); qH[(grow+r)*72 + j*16+l15]=hh; qL[(grow+r)*72 + j*16+l15]=ll;
        split2(ak[j][r],&hh,&ll); kH[(grow+r)*72 + j*16+l15]=hh; kL[(grow+r)*72 + j*16+l15]=ll;
        split2(av[j][r],&hh,&ll); vTH[(j*16+l15)*72 + grow+r]=hh; vTL[(j*16+l15)*72 + grow+r]=ll;
      }
    }
  }
  __syncthreads();

  // scores + softmax -> P
  {
    f32x4 sc[4]={};
    #pragma unroll
    for (int ks=0; ks<2; ks++){
      const int koff = ks*32 + lq*8;
      short8v aHf = *(const short8v*)&qH[(wave*16+l15)*72 + koff];
      short8v aLf = *(const short8v*)&qL[(wave*16+l15)*72 + koff];
      #pragma unroll
      for (int jt=0; jt<4; jt++){
        const int boff = (jt*16+l15)*72 + koff;
        short8v bH = *(const short8v*)&kH[boff];
        short8v bL = *(const short8v*)&kL[boff];
        sc[jt]=MFMA16(aHf,bH,sc[jt],0,0,0); sc[jt]=MFMA16(aHf,bL,sc[jt],0,0,0); sc[jt]=MFMA16(aLf,bH,sc[jt],0,0,0);
      }
    }
    #pragma unroll
    for (int r=0;r<4;r++){
      float s0=sc[0][r]*0.125f, s1=sc[1][r]*0.125f, s2=sc[2][r]*0.125f, s3=sc[3][r]*0.125f;
      float mx = fmaxf(fmaxf(s0,s1),fmaxf(s2,s3));
      mx=fmaxf(mx,__shfl_xor(mx,1)); mx=fmaxf(mx,__shfl_xor(mx,2));
      mx=fmaxf(mx,__shfl_xor(mx,4)); mx=fmaxf(mx,__shfl_xor(mx,8));
      float e0=__expf(s0-mx), e1=__expf(s1-mx), e2=__expf(s2-mx), e3=__expf(s3-mx);
      float se = e0+e1+e2+e3;
      se+=__shfl_xor(se,1); se+=__shfl_xor(se,2); se+=__shfl_xor(se,4); se+=__shfl_xor(se,8);
      float inv = 1.f/se;
      sc[0][r]=e0*inv; sc[1][r]=e1*inv; sc[2][r]=e2*inv; sc[3][r]=e3*inv;
    }
    #pragma unroll
    for (int jt=0; jt<4; jt++)
      #pragma unroll
      for (int r=0;r<4;r++){
        unsigned short hh,ll; split2(sc[jt][r],&hh,&ll);
        pH[(grow+r)*72 + jt*16+l15]=hh; pL[(grow+r)*72 + jt*16+l15]=ll;
      }
  }
  __syncthreads();

  // outst = P @ v
  f32x4 os[4] = {};
  {
    #pragma unroll
    for (int ks=0; ks<2; ks++){
      const int koff = ks*32 + lq*8;
      short8v aHf = *(const short8v*)&pH[(wave*16+l15)*72 + koff];
      short8v aLf = *(const short8v*)&pL[(wave*16+l15)*72 + koff];
      #pragma unroll
      for (int dt=0; dt<4; dt++){
        const int boff = (dt*16+l15)*72 + koff;
        short8v bH = *(const short8v*)&vTH[boff];
        short8v bL = *(const short8v*)&vTL[boff];
        os[dt]=MFMA16(aHf,bH,os[dt],0,0,0); os[dt]=MFMA16(aHf,bL,os[dt],0,0,0); os[dt]=MFMA16(aLf,bH,os[dt],0,0,0);
      }
    }
    #pragma unroll
    for (int dt=0; dt<4; dt++)
      #pragma unroll
      for (int r=0;r<4;r++){
        unsigned short hh,ll; split2(os[dt][r],&hh,&ll);
        oH[(grow+r)*72 + dt*16+l15]=hh; oL[(grow+r)*72 + dt*16+l15]=ll;
      }
  }
  __syncthreads();

  // h1 = silu([st, outst] @ Wg1 + bg1)
  {
    f32x4 ha[4] = {};
    #pragma unroll
    for (int ks=0; ks<4; ks++){
      const int koff2 = (ks&1)*32 + lq*8;
      short8v aHf, aLf;
      if (ks<2){ aHf = *(const short8v*)&stH[(wave*16+l15)*72 + koff2];
                 aLf = *(const short8v*)&stL[(wave*16+l15)*72 + koff2]; }
      else     { aHf = *(const short8v*)&oH[(wave*16+l15)*72 + koff2];
                 aLf = *(const short8v*)&oL[(wave*16+l15)*72 + koff2]; }
      #pragma unroll
      for (int dt=0; dt<4; dt++){
        const int boff = (dt*16+l15)*128 + ks*32 + lq*8;
        short8v bH = *(const short8v*)(Wg1TH+boff);
        short8v bL = *(const short8v*)(Wg1TL+boff);
        ha[dt]=MFMA16(aHf,bH,ha[dt],0,0,0); ha[dt]=MFMA16(aHf,bL,ha[dt],0,0,0); ha[dt]=MFMA16(aLf,bH,ha[dt],0,0,0);
      }
    }
    #pragma unroll
    for (int dt=0; dt<4; dt++){
      float bg = bg1[dt*16+l15];
      #pragma unroll
      for (int r=0;r<4;r++){
        float s = ha[dt][r] + bg;
        float sv = s/(1.f+__expf(-s));
        unsigned short hh,ll; split2(sv,&hh,&ll);
        h1H[(grow+r)*72 + dt*16+l15]=hh; h1L[(grow+r)*72 + dt*16+l15]=ll;
      }
    }
  }
  __syncthreads();

  // gated = sigmoid(h1 @ Wg2 + bg2) * outst
  {
    f32x4 ga[4] = {};
    #pragma unroll
    for (int ks=0; ks<2; ks++){
      const int koff = ks*32 + lq*8;
      short8v aHf = *(const short8v*)&h1H[(wave*16+l15)*72 + koff];
      short8v aLf = *(const short8v*)&h1L[(wave*16+l15)*72 + koff];
      #pragma unroll
      for (int dt=0; dt<4; dt++){
        const int boff = (dt*16+l15)*64 + koff;
        short8v bH = *(const short8v*)(Wg2TH+boff);
        short8v bL = *(const short8v*)(Wg2TL+boff);
        ga[dt]=MFMA16(aHf,bH,ga[dt],0,0,0); ga[dt]=MFMA16(aHf,bL,ga[dt],0,0,0); ga[dt]=MFMA16(aLf,bH,ga[dt],0,0,0);
      }
    }
    #pragma unroll
    for (int dt=0; dt<4; dt++){
      float bg = bg2[dt*16+l15];
      #pragma unroll
      for (int r=0;r<4;r++){
        float gate = 1.f/(1.f+__expf(-(ga[dt][r]+bg)));
        float gv = gate * os[dt][r];
        unsigned short hh,ll; split2(gv,&hh,&ll);
        gH[(grow+r)*72 + dt*16+l15]=hh; gL[(grow+r)*72 + dt*16+l15]=ll;
      }
    }
  }
  __syncthreads();

  // M[c][g] = gated @ Wo[h] -> packed
  {
    f32x4 mac[16] = {};
    #pragma unroll
    for (int ks=0; ks<2; ks++){
      const int koff = ks*32 + lq*8;
      short8v aHf = *(const short8v*)&gH[(wave*16+l15)*72 + koff];
      short8v aLf = *(const short8v*)&gL[(wave*16+l15)*72 + koff];
      #pragma unroll
      for (int ct=0; ct<16; ct++){
        const size_t boff = (size_t)(ct*16+l15)*512 + h*64 + koff;
        short8v bH = *(const short8v*)(WoTH+boff);
        short8v bL = *(const short8v*)(WoTL+boff);
        mac[ct]=MFMA16(aHf,bH,mac[ct],0,0,0); mac[ct]=MFMA16(aHf,bL,mac[ct],0,0,0); mac[ct]=MFMA16(aLf,bH,mac[ct],0,0,0);
      }
    }
    #pragma unroll
    for (int ct=0; ct<16; ct++)
      #pragma unroll
      for (int r=0;r<4;r++){
        unsigned short hh,ll; split2(mac[ct][r],&hh,&ll);
        MtP[(size_t)bh*16384 + (size_t)(ct*16+l15)*64 + grow + r] =
          (unsigned)hh | ((unsigned)ll<<16);
      }
  }
}

// ---------------------------------------------------------------------------
// K4 v3 (round-18): grid 1024; full 256-col output per block.
// ---------------------------------------------------------------------------
__global__ __launch_bounds__(256,2) void k4_out(
  const unsigned* __restrict__ swT, const unsigned* __restrict__ MtP,
  const float* __restrict__ bo, float* __restrict__ out)
{
  __shared__ unsigned short AH[64*72], AL[64*72];
  __shared__ unsigned short BH[128*72], BL[128*72];
  const int tid = threadIdx.x;
  const int wave = tid>>6, lane = tid&63, l15 = lane&15, lq = lane>>4;
  const int m0 = blockIdx.x*64;
  const int b = m0>>15, nn = m0 & 32767;
  f32x4 acc[16] = {};

  for (int hh=0; hh<8; hh++){
    const int bhh = b*8 + hh;
    __syncthreads();
    {
      const int g = tid>>2, mq = (tid&3)*16;
      const unsigned* src = swT + ((size_t)bhh*64 + g)*NSEQ + nn + mq;
      #pragma unroll
      for (int i=0;i<4;i++){
        uint4 pv = *(const uint4*)(src + i*4);
        unsigned u[4]={pv.x,pv.y,pv.z,pv.w};
        #pragma unroll
        for (int j=0;j<4;j++){
          int m = mq + i*4 + j;
          AH[m*72+g] = (unsigned short)(u[j] & 0xFFFFu);
          AL[m*72+g] = (unsigned short)(u[j] >> 16);
        }
      }
    }
    #pragma unroll
    for (int chalf=0; chalf<2; chalf++){
      {
        const int c = tid>>1, gq = (tid&1)*32;
        const unsigned* bsrc = MtP + (size_t)bhh*16384 + (size_t)(chalf*128 + c)*64 + gq;
        #pragma unroll
        for (int i=0;i<8;i++){
          uint4 pv = *(const uint4*)(bsrc + i*4);
          ushort4 hh4, ll4;
          hh4.x=(unsigned short)(pv.x&0xFFFFu); ll4.x=(unsigned short)(pv.x>>16);
          hh4.y=(unsigned short)(pv.y&0xFFFFu); ll4.y=(unsigned short)(pv.y>>16);
          hh4.z=(unsigned short)(pv.z&0xFFFFu); ll4.z=(unsigned short)(pv.z>>16);
          hh4.w=(unsigned short)(pv.w&0xFFFFu); ll4.w=(unsigned short)(pv.w>>16);
          *(ushort4*)&BH[c*72 + gq + i*4] = hh4;
          *(ushort4*)&BL[c*72 + gq + i*4] = ll4;
        }
      }
      __syncthreads();
      #pragma unroll
      for (int ks=0; ks<2; ks++){
        const int koff = ks*32 + lq*8;
        short8v aH = *(const short8v*)&AH[(wave*16+l15)*72 + koff];
        short8v aL = *(const short8v*)&AL[(wave*16+l15)*72 + koff];
        #pragma unroll
        for (int ct=0; ct<8; ct++){
          short8v bH = *(const short8v*)&BH[(ct*16+l15)*72 + koff];
          short8v bL = *(const short8v*)&BL[(ct*16+l15)*72 + koff];
          acc[chalf*8+ct] = MFMA16(aH,bH,acc[chalf*8+ct],0,0,0);
          acc[chalf*8+ct] = MFMA16(aH,bL,acc[chalf*8+ct],0,0,0);
          acc[chalf*8+ct] = MFMA16(aL,bH,acc[chalf*8+ct],0,0,0);
        }
      }
      __syncthreads();
    }
  }
  #pragma unroll
  for (int ci=0; ci<16; ci++)
    #pragma unroll
    for (int r=0;r<4;r++){
      int c = (ci>>3)*128 + (ci&7)*16 + l15;
      out[(size_t)(m0 + wave*16 + lq*4 + r)*256 + c] = acc[ci][r] + bo[c];
    }
}

// ---------------------------------------------------------------------------
extern "C" void kernel_launch(void* const* d_in, const int* in_sizes, int n_in,
                              void* d_out, int out_size, void* d_ws, size_t ws_size,
                              hipStream_t stream) {
  (void)in_sizes; (void)n_in; (void)out_size;
  const float* x    = (const float*)d_in[0];
  const float* pos  = (const float*)d_in[1];
  const float* gum  = (const float*)d_in[2];
  const float* Wx   = (const float*)d_in[3];
  const float* bx   = (const float*)d_in[4];
  const float* W1   = (const float*)d_in[5];
  const float* b1   = (const float*)d_in[6];
  const float* W2   = (const float*)d_in[7];
  const float* b2   = (const float*)d_in[8];
  const float* bias = (const float*)d_in[9];
  const float* Wr   = (const float*)d_in[10];
  const float* br   = (const float*)d_in[11];
  const float* Ws   = (const float*)d_in[12];
  const float* bs   = (const float*)d_in[13];
  const float* Wq   = (const float*)d_in[14];
  const float* Wk   = (const float*)d_in[15];
  const float* Wv   = (const float*)d_in[16];
  const float* Wg1  = (const float*)d_in[17];
  const float* bg1  = (const float*)d_in[18];
  const float* Wg2  = (const float*)d_in[19];
  const float* bg2  = (const float*)d_in[20];
  const float* Wo   = (const float*)d_in[21];
  const float* bo   = (const float*)d_in[22];
  float* out = (float*)d_out;

  unsigned* xmidP = (unsigned*)d_ws;                    // 33,554,432 uints
  unsigned* swT   = xmidP + (size_t)33554432;
  float*    partp = (float*)(swT + (size_t)33554432);
  float*    stred = partp + (size_t)4259840;
  unsigned short* WxTH = (unsigned short*)(stred + (size_t)66560);
  unsigned short* WxTL  = WxTH + (size_t)131072;
  unsigned short* WqTH  = WxTL + (size_t)131072;
  unsigned short* WqTL  = WqTH + 4096;
  unsigned short* WkTH  = WqTL + 4096;
  unsigned short* WkTL  = WkTH + 4096;
  unsigned short* WvTH  = WkTL + 4096;
  unsigned short* WvTL  = WvTH + 4096;
  unsigned short* Wg1TH = WvTL + 4096;
  unsigned short* Wg1TL = Wg1TH + 8192;
  unsigned short* Wg2TH = Wg1TL + 8192;
  unsigned short* Wg2TL = Wg2TH + 4096;
  unsigned short* WoTH  = Wg2TL + 4096;
  unsigned short* WoTL  = WoTH + (size_t)131072;
  unsigned short* W1TH  = WoTL + (size_t)131072;
  unsigned short* W1TL  = W1TH + 4096;
  unsigned short* WsTH  = W1TL + 4096;
  unsigned short* WsTL  = WsTH + 4096;
  unsigned* MtP = (unsigned*)partp;  // alias: part dead after k3a
  const size_t need = ((size_t)33554432*2 + 4259840 + 66560)*4 + (size_t)589824*2;
  if (ws_size < need) return;

  k0_prep<<<512, 256, 0, stream>>>(Wx, WxTH, WxTL);
  k0b_prep<<<11, 256, 0, stream>>>(Wq, Wk, Wv, Wg1, Wg2, Wo, W1, Ws,
      WqTH,WqTL,WkTH,WkTL,WvTH,WvTL,Wg1TH,Wg1TL,Wg2TH,Wg2TL,WoTH,WoTL,W1TH,W1TL,WsTH,WsTL);
  k1_gemm_rope<<<1024, 256, 0, stream>>>(x, pos, WxTH, WxTL, bx, Wr, br, xmidP);
  k2_tile<<<dim3(64,16), 256, 0, stream>>>(xmidP, gum, W1TH, W1TL, b1, W2, b2, bias, WsTH, WsTL, bs, swT, partp);
  k3a_reduce<<<dim3(16,17), 256, 0, stream>>>(partp, stred);
  k3b_slice<<<16, 256, 0, stream>>>(stred, WqTH,WqTL,WkTH,WkTL,WvTH,WvTL,
      Wg1TH,Wg1TL,Wg2TH,Wg2TL,WoTH,WoTL, bg1, bg2, MtP);
  k4_out<<<1024, 256, 0, stream>>>(swT, MtP, bo, out);
}

// Round 20
// 391.234 us; speedup vs baseline: 1.0353x; 1.0353x over previous
//
#include <hip/hip_runtime.h>
#include <math.h>

#define NSEQ 32768

using short8v = __attribute__((ext_vector_type(8))) short;
using f32x4   = __attribute__((ext_vector_type(4))) float;
#define MFMA16 __builtin_amdgcn_mfma_f32_16x16x32_bf16

__device__ __forceinline__ unsigned short f2bf(float f){
  union{float f; unsigned u;} v; v.f = f;
  return (unsigned short)((v.u + 0x7FFFu + ((v.u>>16)&1u))>>16);
}
__device__ __forceinline__ float bf2f(unsigned short h){
  union{unsigned u; float f;} v; v.u = ((unsigned)h)<<16; return v.f;
}
__device__ __forceinline__ void split2(float f, unsigned short* h, unsigned short* l){
  unsigned short hh = f2bf(f);
  *h = hh; *l = f2bf(f - bf2f(hh));
}
__device__ __forceinline__ float gelu_f(float x){
  return 0.5f*x*(1.f + erff(x*0.70710678118654752f));
}

// ---------------------------------------------------------------------------
// K0: Wx [256][512] fp32 -> WxTH/WxTL [512][256] split-bf16 (transposed). Once.
// ---------------------------------------------------------------------------
__global__ __launch_bounds__(256) void k0_prep(const float* __restrict__ Wx,
    unsigned short* __restrict__ WxTH, unsigned short* __restrict__ WxTL)
{
  const int n = blockIdx.x;
  const int k = threadIdx.x;
  float v = Wx[(size_t)k*512 + n];
  unsigned short hh, ll; split2(v,&hh,&ll);
  WxTH[n*256+k]=hh; WxTL[n*256+k]=ll;
}

// ---------------------------------------------------------------------------
// K0b: prep all small weights as transposed split-bf16. grid 11 x 256.
// ---------------------------------------------------------------------------
__global__ __launch_bounds__(256) void k0b_prep(
  const float* __restrict__ Wq, const float* __restrict__ Wk, const float* __restrict__ Wv,
  const float* __restrict__ Wg1, const float* __restrict__ Wg2, const float* __restrict__ Wo,
  const float* __restrict__ W1, const float* __restrict__ Ws,
  unsigned short* __restrict__ WqTH, unsigned short* __restrict__ WqTL,
  unsigned short* __restrict__ WkTH, unsigned short* __restrict__ WkTL,
  unsigned short* __restrict__ WvTH, unsigned short* __restrict__ WvTL,
  unsigned short* __restrict__ Wg1TH, unsigned short* __restrict__ Wg1TL,
  unsigned short* __restrict__ Wg2TH, unsigned short* __restrict__ Wg2TL,
  unsigned short* __restrict__ WoTH, unsigned short* __restrict__ WoTL,
  unsigned short* __restrict__ W1TH, unsigned short* __restrict__ W1TL,
  unsigned short* __restrict__ WsTH, unsigned short* __restrict__ WsTL)
{
  const int bx = blockIdx.x, t = threadIdx.x;
  unsigned short hh, ll;
  if (bx == 0){
    for (int i=0;i<16;i++){ int idx=i*256+t; int r=idx>>6, c=idx&63;
      split2(Wq[r*64+c],&hh,&ll); WqTH[c*64+r]=hh; WqTL[c*64+r]=ll;
      split2(Wk[r*64+c],&hh,&ll); WkTH[c*64+r]=hh; WkTL[c*64+r]=ll;
      split2(Wv[r*64+c],&hh,&ll); WvTH[c*64+r]=hh; WvTL[c*64+r]=ll;
    }
  } else if (bx == 1){
    for (int i=0;i<32;i++){ int idx=i*256+t; int r=idx>>6, c=idx&63;
      split2(Wg1[r*64+c],&hh,&ll); Wg1TH[c*128+r]=hh; Wg1TL[c*128+r]=ll;
    }
  } else if (bx == 2){
    for (int i=0;i<16;i++){ int idx=i*256+t; int r=idx>>6, c=idx&63;
      split2(Wg2[r*64+c],&hh,&ll); Wg2TH[c*64+r]=hh; Wg2TL[c*64+r]=ll;
      split2(W1[r*64+c],&hh,&ll);  W1TH[c*64+r]=hh;  W1TL[c*64+r]=ll;
      split2(Ws[r*64+c],&hh,&ll);  WsTH[c*64+r]=hh;  WsTL[c*64+r]=ll;
    }
  } else {
    int kb = (bx-3)*64;
    for (int i=0;i<64;i++){ int k = kb+i;
      split2(Wo[(size_t)k*256 + t],&hh,&ll);
      WoTH[(size_t)t*512 + k]=hh; WoTL[(size_t)t*512 + k]=ll;
    }
  }
}

// ---------------------------------------------------------------------------
// K1 v3: 256 threads, 64 tokens/block, grid 1024. fp32 xmid out.
// ---------------------------------------------------------------------------
__global__ __launch_bounds__(256,2) void k1_gemm_rope(
    const float* __restrict__ x, const float* __restrict__ pos,
    const unsigned short* __restrict__ WxTH, const unsigned short* __restrict__ WxTL,
    const float* __restrict__ bx,
    const float* __restrict__ Wr, const float* __restrict__ br,
    float* __restrict__ xmid)
{
  __shared__ unsigned short SA[2*64*128];
  __shared__ unsigned short SB[2*64*128];
  __shared__ float trig[64][8];
  const int tid = threadIdx.x;
  const int wave = tid>>6, lane = tid&63, l15 = lane&15, lq = lane>>4;
  const int m0 = blockIdx.x*64;

  if (tid < 64){
    int m = m0 + tid;
    float a0 = pos[m*3+0];
    float a1 = pos[m*3+1] * 0.046415888336127774f;
    float a2 = pos[m*3+2] * 0.002154434690031884f;
    trig[tid][0]=sinf(a0); trig[tid][1]=sinf(a1); trig[tid][2]=sinf(a2);
    trig[tid][3]=cosf(a0); trig[tid][4]=cosf(a1); trig[tid][5]=cosf(a2);
  }

  short8v aHr[8], aLr[8];
  {
    const int lm = tid>>2, lkq = (tid&3)*32;
    #pragma unroll
    for (int kh=0; kh<2; kh++){
      __syncthreads();
      const float* src = x + (size_t)(m0+lm)*256 + kh*128 + lkq;
      #pragma unroll
      for (int i=0;i<8;i++){
        float4 v = *(const float4*)(src + i*4);
        ushort4 hh, ll;
        split2(v.x,&hh.x,&ll.x); split2(v.y,&hh.y,&ll.y);
        split2(v.z,&hh.z,&ll.z); split2(v.w,&hh.w,&ll.w);
        int G = (lkq>>3) + (i>>1);
        int idx = lm*128 + (((G ^ (lm&15)))<<3) + ((i&1)<<2);
        *(ushort4*)&SA[idx] = hh;
        *(ushort4*)&SA[64*128 + idx] = ll;
      }
      __syncthreads();
      const int row = wave*16 + l15;
      #pragma unroll
      for (int ks=0; ks<4; ks++){
        int idx = row*128 + ((((ks<<2)+lq) ^ l15)<<3);
        aHr[kh*4+ks] = *(const short8v*)&SA[idx];
        aLr[kh*4+ks] = *(const short8v*)&SA[64*128 + idx];
      }
    }
  }

  float ropev[4][4];
  #pragma unroll
  for (int r=0;r<4;r++){
    int tk = wave*16 + lq*4 + r;
    float t0=trig[tk][0],t1=trig[tk][1],t2=trig[tk][2];
    float t3=trig[tk][3],t4=trig[tk][4],t5=trig[tk][5];
    #pragma unroll
    for (int j=0;j<4;j++){
      int d = j*16 + l15;
      float v = br[d];
      v = fmaf(t0, Wr[0*64+d], v);
      v = fmaf(t1, Wr[1*64+d], v);
      v = fmaf(t2, Wr[2*64+d], v);
      v = fmaf(t3, Wr[3*64+d], v);
      v = fmaf(t4, Wr[4*64+d], v);
      v = fmaf(t5, Wr[5*64+d], v);
      ropev[r][j] = v;
    }
  }

  const int bidx = m0 >> 15;
  const int nbase = (m0 & 32767) + wave*16 + lq*4;
  const int ln = tid>>2, lnkq = (tid&3)*32;

  for (int h=0; h<8; h++){
    f32x4 acc[4] = {};
    #pragma unroll
    for (int kh=0; kh<2; kh++){
      __syncthreads();
      {
        const unsigned short* sH = WxTH + (size_t)(h*64+ln)*256 + kh*128 + lnkq;
        const unsigned short* sL = WxTL + (size_t)(h*64+ln)*256 + kh*128 + lnkq;
        int g0 = lnkq>>3;
        #pragma unroll
        for (int i=0;i<4;i++){
          int idx = ln*128 + (((g0+i) ^ (ln&15))<<3);
          *(uint4*)&SB[idx]          = *(const uint4*)(sH + i*8);
          *(uint4*)&SB[64*128 + idx] = *(const uint4*)(sL + i*8);
        }
      }
      __syncthreads();
      #pragma unroll
      for (int ks=0; ks<4; ks++){
        short8v a_h = aHr[kh*4+ks], a_l = aLr[kh*4+ks];
        #pragma unroll
        for (int j=0;j<4;j++){
          int idx = (j*16+l15)*128 + ((((ks<<2)+lq) ^ l15)<<3);
          short8v b_h = *(const short8v*)&SB[idx];
          short8v b_l = *(const short8v*)&SB[64*128 + idx];
          acc[j] = MFMA16(a_h,b_h,acc[j],0,0,0);
          acc[j] = MFMA16(a_h,b_l,acc[j],0,0,0);
          acc[j] = MFMA16(a_l,b_h,acc[j],0,0,0);
        }
      }
    }
    #pragma unroll
    for (int j=0;j<4;j++){
      int col = j*16 + l15;
      float bxv = bx[h*64+col];
      #pragma unroll
      for (int r=0;r<4;r++){
        xmid[(((size_t)(bidx*8+h))*NSEQ + nbase + r)*64 + col] =
          acc[j][r] + bxv + ropev[r][j];
      }
    }
  }
}

// ---------------------------------------------------------------------------
// K2 v7: 2 barriers/subtile (verified round 16).
// ---------------------------------------------------------------------------
__global__ __launch_bounds__(256,2) void k2_tile(
  const float* __restrict__ xmid, const float* __restrict__ gum,
  const unsigned short* __restrict__ W1TH, const unsigned short* __restrict__ W1TL,
  const float* __restrict__ b1,
  const float* __restrict__ W2, const float* __restrict__ b2,
  const float* __restrict__ biasp,
  const unsigned short* __restrict__ WsTH, const unsigned short* __restrict__ WsTL,
  const float* __restrict__ bs,
  unsigned* __restrict__ swT, float* __restrict__ part)
{
  __shared__ unsigned short XBh[64*72], XBl[64*72];
  __shared__ unsigned short W1h[64*72], W1l[64*72];
  __shared__ unsigned short Wsh[64*72], Wsl[64*72];
  __shared__ unsigned short swh[64*72], swl[64*72];
  __shared__ float snred[4*64];
  __shared__ float prm[200];

  const int tid = threadIdx.x;
  const int wave = tid>>6, lane = tid&63, l15 = lane&15, lq = lane>>4;
  const int bh = blockIdx.y, chunk = blockIdx.x, h = bh&7;
  const size_t rowbase = (size_t)bh*NSEQ;

  {
    const int g = tid>>2, c16 = (tid&3)*16;
    *(uint4*)&W1h[g*72+c16]   = *(const uint4*)(W1TH + g*64 + c16);
    *(uint4*)&W1h[g*72+c16+8] = *(const uint4*)(W1TH + g*64 + c16 + 8);
    *(uint4*)&W1l[g*72+c16]   = *(const uint4*)(W1TL + g*64 + c16);
    *(uint4*)&W1l[g*72+c16+8] = *(const uint4*)(W1TL + g*64 + c16 + 8);
    *(uint4*)&Wsh[g*72+c16]   = *(const uint4*)(WsTH + g*64 + c16);
    *(uint4*)&Wsh[g*72+c16+8] = *(const uint4*)(WsTH + g*64 + c16 + 8);
    *(uint4*)&Wsl[g*72+c16]   = *(const uint4*)(WsTL + g*64 + c16);
    *(uint4*)&Wsl[g*72+c16+8] = *(const uint4*)(WsTL + g*64 + c16 + 8);
  }
  if (tid<64){ prm[tid]=b1[tid]; prm[64+tid]=bs[tid]; prm[128+tid]=W2[tid]; }
  if (tid==64){ prm[192]=b2[0]; prm[193]=biasp[h]; }
  __syncthreads();

  f32x4 acc2[4] = {};
  float snacc[4][4] = {};
  const int mloc = wave*16 + l15;
  const int mq = (tid>>4)*4, dq = (tid&15)*4;

  for (int sub=0; sub<8; ++sub){
    const int n0 = chunk*512 + sub*64;

    {
      const float* src = xmid + (rowbase + n0 + mq)*64 + dq;
      unsigned short hh[4][4], ll[4][4];
      #pragma unroll
      for (int i=0;i<4;i++){
        float4 v = *(const float4*)(src + (size_t)i*64);
        split2(v.x,&hh[i][0],&ll[i][0]); split2(v.y,&hh[i][1],&ll[i][1]);
        split2(v.z,&hh[i][2],&ll[i][2]); split2(v.w,&hh[i][3],&ll[i][3]);
      }
      #pragma unroll
      for (int j=0;j<4;j++){
        int d = dq+j;
        ushort4 th; th.x=hh[0][j]; th.y=hh[1][j]; th.z=hh[2][j]; th.w=hh[3][j];
        ushort4 tl; tl.x=ll[0][j]; tl.y=ll[1][j]; tl.z=ll[2][j]; tl.w=ll[3][j];
        *(ushort4*)&XBh[d*72 + mq] = th;
        *(ushort4*)&XBl[d*72 + mq] = tl;
      }
    }

    float4 xf[4];
    {
      const float* xrow = xmid + (rowbase + n0 + mloc)*64;
      #pragma unroll
      for (int ks=0; ks<2; ks++){
        const int koff = ks*32 + lq*8;
        xf[ks*2]   = *(const float4*)(xrow + koff);
        xf[ks*2+1] = *(const float4*)(xrow + koff + 4);
      }
    }
    const float* grow = gum + (rowbase + n0 + mloc)*64;
    float4 gu[4];
    #pragma unroll
    for (int gt=0; gt<4; gt++) gu[gt] = *(const float4*)(grow + gt*16 + lq*4);

    f32x4 t1a[4] = {}, lga[4] = {};
    #pragma unroll
    for (int ks=0; ks<2; ks++){
      const int koff = ks*32 + lq*8;
      float xv[8] = {xf[ks*2].x,xf[ks*2].y,xf[ks*2].z,xf[ks*2].w,
                     xf[ks*2+1].x,xf[ks*2+1].y,xf[ks*2+1].z,xf[ks*2+1].w};
      short8v xH, xL;
      #pragma unroll
      for (int j=0;j<8;j++){
        unsigned short hh,ll; split2(xv[j],&hh,&ll);
        xH[j]=(short)hh; xL[j]=(short)ll;
      }
      #pragma unroll
      for (int gt=0; gt<4; gt++){
        const int aoff = (gt*16+l15)*72 + koff;
        short8v wH = *(const short8v*)&W1h[aoff];
        short8v wL = *(const short8v*)&W1l[aoff];
        t1a[gt] = MFMA16(wH,xH,t1a[gt],0,0,0);
        t1a[gt] = MFMA16(wH,xL,t1a[gt],0,0,0);
        t1a[gt] = MFMA16(wL,xH,t1a[gt],0,0,0);
        short8v sH = *(const short8v*)&Wsh[aoff];
        short8v sL = *(const short8v*)&Wsl[aoff];
        lga[gt] = MFMA16(sH,xH,lga[gt],0,0,0);
        lga[gt] = MFMA16(sH,xL,lga[gt],0,0,0);
        lga[gt] = MFMA16(sL,xH,lga[gt],0,0,0);
      }
    }

    float p = 0.f;
    #pragma unroll
    for (int gt=0; gt<4; gt++)
      #pragma unroll
      for (int r=0;r<4;r++){
        int g = gt*16 + lq*4 + r;
        p += gelu_f(t1a[gt][r] + prm[g]) * prm[128+g];
      }
    p += __shfl_xor(p,16); p += __shfl_xor(p,32);
    float t2 = gelu_f(p + prm[192]);
    float rtemp = 1.f / fmaxf(t2 + prm[193], 0.01f);

    float z[4][4]; float mx = -1e30f;
    #pragma unroll
    for (int gt=0; gt<4; gt++){
      float guv[4] = {gu[gt].x, gu[gt].y, gu[gt].z, gu[gt].w};
      #pragma unroll
      for (int r=0;r<4;r++){
        int g = gt*16 + lq*4 + r;
        float gn = -__logf(-__logf(guv[r]+1e-8f)+1e-8f);
        float zz = (lga[gt][r] + prm[64+g] + gn)*rtemp;
        z[gt][r]=zz; mx = fmaxf(mx, zz);
      }
    }
    mx = fmaxf(mx, __shfl_xor(mx,16)); mx = fmaxf(mx, __shfl_xor(mx,32));
    float se = 0.f;
    #pragma unroll
    for (int gt=0; gt<4; gt++)
      #pragma unroll
      for (int r=0;r<4;r++){ float e = __expf(z[gt][r]-mx); z[gt][r]=e; se += e; }
    se += __shfl_xor(se,16); se += __shfl_xor(se,32);
    float inv = 1.f/se;
    #pragma unroll
    for (int gt=0; gt<4; gt++)
      #pragma unroll
      for (int r=0;r<4;r++){
        float swv = z[gt][r]*inv;
        snacc[gt][r] += swv;
        int g = gt*16 + lq*4 + r;
        unsigned short hh,ll; split2(swv,&hh,&ll);
        swh[g*72 + mloc] = hh; swl[g*72 + mloc] = ll;
      }

    __syncthreads();   // A

    {
      const int g = tid>>2, mq2 = (tid&3)*16;
      #pragma unroll
      for (int i=0;i<4;i++){
        ushort4 hh = *(const ushort4*)&swh[g*72 + mq2 + i*4];
        ushort4 ll = *(const ushort4*)&swl[g*72 + mq2 + i*4];
        uint4 pk;
        pk.x = (unsigned)hh.x | ((unsigned)ll.x<<16);
        pk.y = (unsigned)hh.y | ((unsigned)ll.y<<16);
        pk.z = (unsigned)hh.z | ((unsigned)ll.z<<16);
        pk.w = (unsigned)hh.w | ((unsigned)ll.w<<16);
        *(uint4*)(swT + ((size_t)bh*64 + g)*NSEQ + n0 + mq2 + i*4) = pk;
      }
    }

    #pragma unroll
    for (int ks=0; ks<2; ks++){
      const int koff = ks*32 + lq*8;
      short8v aH = *(const short8v*)&swh[(wave*16+l15)*72 + koff];
      short8v aL = *(const short8v*)&swl[(wave*16+l15)*72 + koff];
      #pragma unroll
      for (int dt=0; dt<4; dt++){
        const int d = dt*16 + l15;
        short8v bH = *(const short8v*)&XBh[d*72 + koff];
        short8v bL = *(const short8v*)&XBl[d*72 + koff];
        acc2[dt] = MFMA16(aH,bH,acc2[dt],0,0,0);
        acc2[dt] = MFMA16(aH,bL,acc2[dt],0,0,0);
        acc2[dt] = MFMA16(aL,bH,acc2[dt],0,0,0);
      }
    }

    __syncthreads();   // B
  }

  float* pb = part + ((size_t)bh*64 + chunk)*4160;
  #pragma unroll
  for (int dt=0; dt<4; dt++)
    #pragma unroll
    for (int r=0;r<4;r++){
      int g = wave*16 + lq*4 + r;
      int d = dt*16 + l15;
      pb[g*64 + d] = acc2[dt][r];
    }
  #pragma unroll
  for (int gt=0; gt<4; gt++)
    #pragma unroll
    for (int r=0;r<4;r++){
      float v = snacc[gt][r];
      v += __shfl_xor(v,1); v += __shfl_xor(v,2);
      v += __shfl_xor(v,4); v += __shfl_xor(v,8);
      if (l15==0) snred[wave*64 + gt*16 + lq*4 + r] = v;
    }
  __syncthreads();
  if (tid < 64){
    float s = 0.f;
    #pragma unroll
    for (int w=0; w<4; w++) s += snred[w*64 + tid];
    pb[4096 + tid] = s;
  }
}

// ---------------------------------------------------------------------------
// K3a: reduce 64 chunk-partials -> stred[bh][4160]. grid (16, 17)
// ---------------------------------------------------------------------------
__global__ __launch_bounds__(256) void k3a_reduce(
    const float* __restrict__ part, float* __restrict__ stred)
{
  const int bh = blockIdx.x;
  const int i = blockIdx.y*256 + threadIdx.x;
  if (i >= 4160) return;
  const float* pb = part + (size_t)bh*64*4160 + i;
  float s[8] = {};
  #pragma unroll 2
  for (int c=0; c<64; c+=8)
    #pragma unroll
    for (int j=0;j<8;j++) s[j] += pb[(size_t)(c+j)*4160];
  stred[bh*4160 + i] = ((s[0]+s[1])+(s[2]+s[3])) + ((s[4]+s[5])+(s[6]+s[7]));
}

// ---------------------------------------------------------------------------
// K3b: per (b,h), 4 waves, all matmuls split-bf16 MFMA. Mt written PACKED.
// ---------------------------------------------------------------------------
__global__ __launch_bounds__(256) void k3b_slice(
    const float* __restrict__ stred,
    const unsigned short* __restrict__ WqTH, const unsigned short* __restrict__ WqTL,
    const unsigned short* __restrict__ WkTH, const unsigned short* __restrict__ WkTL,
    const unsigned short* __restrict__ WvTH, const unsigned short* __restrict__ WvTL,
    const unsigned short* __restrict__ Wg1TH, const unsigned short* __restrict__ Wg1TL,
    const unsigned short* __restrict__ Wg2TH, const unsigned short* __restrict__ Wg2TL,
    const unsigned short* __restrict__ WoTH, const unsigned short* __restrict__ WoTL,
    const float* __restrict__ bg1, const float* __restrict__ bg2,
    unsigned* __restrict__ MtP)
{
  __shared__ unsigned short stH[64*72], stL[64*72];
  __shared__ unsigned short qH[64*72],  qL[64*72];
  __shared__ unsigned short kH[64*72],  kL[64*72];
  __shared__ unsigned short vTH[64*72], vTL[64*72];
  __shared__ unsigned short pH[64*72],  pL[64*72];
  __shared__ unsigned short oH[64*72],  oL[64*72];
  __shared__ unsigned short h1H[64*72], h1L[64*72];
  __shared__ unsigned short gH[64*72],  gL[64*72];
  __shared__ float snl[64];

  const int tid = threadIdx.x;
  const int wave = tid>>6, lane = tid&63, l15 = lane&15, lq = lane>>4;
  const int bh = blockIdx.x, h = bh&7;
  const int grow = wave*16 + lq*4;

  if (tid < 64) snl[tid] = stred[bh*4160 + 4096 + tid] + 1e-5f;
  __syncthreads();
  {
    const int g = tid>>2, doff = (tid&3)*16;
    const float sn = snl[g];
    #pragma unroll
    for (int i=0;i<4;i++){
      float4 v = *(const float4*)(stred + bh*4160 + g*64 + doff + i*4);
      ushort4 hh, ll;
      split2(v.x/sn,&hh.x,&ll.x); split2(v.y/sn,&hh.y,&ll.y);
      split2(v.z/sn,&hh.z,&ll.z); split2(v.w/sn,&hh.w,&ll.w);
      *(ushort4*)&stH[g*72 + doff + i*4] = hh;
      *(ushort4*)&stL[g*72 + doff + i*4] = ll;
    }
  }
  __syncthreads();

  // QKV
  {
    f32x4 aq[4]={}, ak[4]={}, av[4]={};
    #pragma unroll
    for (int ks=0; ks<2; ks++){
      const int koff = ks*32 + lq*8;
      short8v sH = *(const short8v*)&stH[(wave*16+l15)*72 + koff];
      short8v sL = *(const short8v*)&stL[(wave*16+l15)*72 + koff];
      #pragma unroll
      for (int j=0;j<4;j++){
        const int boff = (j*16+l15)*64 + koff;
        short8v bH, bL;
        bH = *(const short8v*)(WqTH+boff); bL = *(const short8v*)(WqTL+boff);
        aq[j]=MFMA16(sH,bH,aq[j],0,0,0); aq[j]=MFMA16(sH,bL,aq[j],0,0,0); aq[j]=MFMA16(sL,bH,aq[j],0,0,0);
        bH = *(const short8v*)(WkTH+boff); bL = *(const short8v*)(WkTL+boff);
        ak[j]=MFMA16(sH,bH,ak[j],0,0,0); ak[j]=MFMA16(sH,bL,ak[j],0,0,0); ak[j]=MFMA16(sL,bH,ak[j],0,0,0);
        bH = *(const short8v*)(WvTH+boff); bL = *(const short8v*)(WvTL+boff);
        av[j]=MFMA16(sH,bH,av[j],0,0,0); av[j]=MFMA16(sH,bL,av[j],0,0,0); av[j]=MFMA16(sL,bH,av[j],0,0,0);
      }
    }
    #pragma unroll
    for (int j=0;j<4;j++){
      #pragma unroll
      for (int r=0;r<4;r++){
        unsigned short hh,ll;
        split2(aq[j][r],&hh,&ll); qH[(grow+r)*72 + j*16+l15]=hh; qL[(grow+r)*72 + j*16+l15]=ll;
        split2(ak[j][r],&hh,&ll); kH[(grow+r)*72 + j*16+l15]=hh; kL[(grow+r)*72 + j*16+l15]=ll;
        split2(av[j][r],&hh,&ll); vTH[(j*16+l15)*72 + grow+r]=hh; vTL[(j*16+l15)*72 + grow+r]=ll;
      }
    }
  }
  __syncthreads();

  // scores + softmax -> P
  {
    f32x4 sc[4]={};
    #pragma unroll
    for (int ks=0; ks<2; ks++){
      const int koff = ks*32 + lq*8;
      short8v aHf = *(const short8v*)&qH[(wave*16+l15)*72 + koff];
      short8v aLf = *(const short8v*)&qL[(wave*16+l15)*72 + koff];
      #pragma unroll
      for (int jt=0; jt<4; jt++){
        const int boff = (jt*16+l15)*72 + koff;
        short8v bH = *(const short8v*)&kH[boff];
        short8v bL = *(const short8v*)&kL[boff];
        sc[jt]=MFMA16(aHf,bH,sc[jt],0,0,0); sc[jt]=MFMA16(aHf,bL,sc[jt],0,0,0); sc[jt]=MFMA16(aLf,bH,sc[jt],0,0,0);
      }
    }
    #pragma unroll
    for (int r=0;r<4;r++){
      float s0=sc[0][r]*0.125f, s1=sc[1][r]*0.125f, s2=sc[2][r]*0.125f, s3=sc[3][r]*0.125f;
      float mx = fmaxf(fmaxf(s0,s1),fmaxf(s2,s3));
      mx=fmaxf(mx,__shfl_xor(mx,1)); mx=fmaxf(mx,__shfl_xor(mx,2));
      mx=fmaxf(mx,__shfl_xor(mx,4)); mx=fmaxf(mx,__shfl_xor(mx,8));
      float e0=__expf(s0-mx), e1=__expf(s1-mx), e2=__expf(s2-mx), e3=__expf(s3-mx);
      float se = e0+e1+e2+e3;
      se+=__shfl_xor(se,1); se+=__shfl_xor(se,2); se+=__shfl_xor(se,4); se+=__shfl_xor(se,8);
      float inv = 1.f/se;
      sc[0][r]=e0*inv; sc[1][r]=e1*inv; sc[2][r]=e2*inv; sc[3][r]=e3*inv;
    }
    #pragma unroll
    for (int jt=0; jt<4; jt++)
      #pragma unroll
      for (int r=0;r<4;r++){
        unsigned short hh,ll; split2(sc[jt][r],&hh,&ll);
        pH[(grow+r)*72 + jt*16+l15]=hh; pL[(grow+r)*72 + jt*16+l15]=ll;
      }
  }
  __syncthreads();

  // outst = P @ v
  f32x4 os[4] = {};
  {
    #pragma unroll
    for (int ks=0; ks<2; ks++){
      const int koff = ks*32 + lq*8;
      short8v aHf = *(const short8v*)&pH[(wave*16+l15)*72 + koff];
      short8v aLf = *(const short8v*)&pL[(wave*16+l15)*72 + koff];
      #pragma unroll
      for (int dt=0; dt<4; dt++){
        const int boff = (dt*16+l15)*72 + koff;
        short8v bH = *(const short8v*)&vTH[boff];
        short8v bL = *(const short8v*)&vTL[boff];
        os[dt]=MFMA16(aHf,bH,os[dt],0,0,0); os[dt]=MFMA16(aHf,bL,os[dt],0,0,0); os[dt]=MFMA16(aLf,bH,os[dt],0,0,0);
      }
    }
    #pragma unroll
    for (int dt=0; dt<4; dt++)
      #pragma unroll
      for (int r=0;r<4;r++){
        unsigned short hh,ll; split2(os[dt][r],&hh,&ll);
        oH[(grow+r)*72 + dt*16+l15]=hh; oL[(grow+r)*72 + dt*16+l15]=ll;
      }
  }
  __syncthreads();

  // h1 = silu([st, outst] @ Wg1 + bg1)
  {
    f32x4 ha[4] = {};
    #pragma unroll
    for (int ks=0; ks<4; ks++){
      const int koff2 = (ks&1)*32 + lq*8;
      short8v aHf, aLf;
      if (ks<2){ aHf = *(const short8v*)&stH[(wave*16+l15)*72 + koff2];
                 aLf = *(const short8v*)&stL[(wave*16+l15)*72 + koff2]; }
      else     { aHf = *(const short8v*)&oH[(wave*16+l15)*72 + koff2];
                 aLf = *(const short8v*)&oL[(wave*16+l15)*72 + koff2]; }
      #pragma unroll
      for (int dt=0; dt<4; dt++){
        const int boff = (dt*16+l15)*128 + ks*32 + lq*8;
        short8v bH = *(const short8v*)(Wg1TH+boff);
        short8v bL = *(const short8v*)(Wg1TL+boff);
        ha[dt]=MFMA16(aHf,bH,ha[dt],0,0,0); ha[dt]=MFMA16(aHf,bL,ha[dt],0,0,0); ha[dt]=MFMA16(aLf,bH,ha[dt],0,0,0);
      }
    }
    #pragma unroll
    for (int dt=0; dt<4; dt++){
      float bg = bg1[dt*16+l15];
      #pragma unroll
      for (int r=0;r<4;r++){
        float s = ha[dt][r] + bg;
        float sv = s/(1.f+__expf(-s));
        unsigned short hh,ll; split2(sv,&hh,&ll);
        h1H[(grow+r)*72 + dt*16+l15]=hh; h1L[(grow+r)*72 + dt*16+l15]=ll;
      }
    }
  }
  __syncthreads();

  // gated = sigmoid(h1 @ Wg2 + bg2) * outst
  {
    f32x4 ga[4] = {};
    #pragma unroll
    for (int ks=0; ks<2; ks++){
      const int koff = ks*32 + lq*8;
      short8v aHf = *(const short8v*)&h1H[(wave*16+l15)*72 + koff];
      short8v aLf = *(const short8v*)&h1L[(wave*16+l15)*72 + koff];
      #pragma unroll
      for (int dt=0; dt<4; dt++){
        const int boff = (dt*16+l15)*64 + koff;
        short8v bH = *(const short8v*)(Wg2TH+boff);
        short8v bL = *(const short8v*)(Wg2TL+boff);
        ga[dt]=MFMA16(aHf,bH,ga[dt],0,0,0); ga[dt]=MFMA16(aHf,bL,ga[dt],0,0,0); ga[dt]=MFMA16(aLf,bH,ga[dt],0,0,0);
      }
    }
    #pragma unroll
    for (int dt=0; dt<4; dt++){
      float bg = bg2[dt*16+l15];
      #pragma unroll
      for (int r=0;r<4;r++){
        float gate = 1.f/(1.f+__expf(-(ga[dt][r]+bg)));
        float gv = gate * os[dt][r];
        unsigned short hh,ll; split2(gv,&hh,&ll);
        gH[(grow+r)*72 + dt*16+l15]=hh; gL[(grow+r)*72 + dt*16+l15]=ll;
      }
    }
  }
  __syncthreads();

  // M[c][g] = gated @ Wo[h] -> packed
  {
    f32x4 mac[16] = {};
    #pragma unroll
    for (int ks=0; ks<2; ks++){
      const int koff = ks*32 + lq*8;
      short8v aHf = *(const short8v*)&gH[(wave*16+l15)*72 + koff];
      short8v aLf = *(const short8v*)&gL[(wave*16+l15)*72 + koff];
      #pragma unroll
      for (int ct=0; ct<16; ct++){
        const size_t boff = (size_t)(ct*16+l15)*512 + h*64 + koff;
        short8v bH = *(const short8v*)(WoTH+boff);
        short8v bL = *(const short8v*)(WoTL+boff);
        mac[ct]=MFMA16(aHf,bH,mac[ct],0,0,0); mac[ct]=MFMA16(aHf,bL,mac[ct],0,0,0); mac[ct]=MFMA16(aLf,bH,mac[ct],0,0,0);
      }
    }
    #pragma unroll
    for (int ct=0; ct<16; ct++)
      #pragma unroll
      for (int r=0;r<4;r++){
        unsigned short hh,ll; split2(mac[ct][r],&hh,&ll);
        MtP[(size_t)bh*16384 + (size_t)(ct*16+l15)*64 + grow + r] =
          (unsigned)hh | ((unsigned)ll<<16);
      }
  }
}

// ---------------------------------------------------------------------------
// K4 v3: grid 1024; full 256-col output per block.
// ---------------------------------------------------------------------------
__global__ __launch_bounds__(256,2) void k4_out(
  const unsigned* __restrict__ swT, const unsigned* __restrict__ MtP,
  const float* __restrict__ bo, float* __restrict__ out)
{
  __shared__ unsigned short AH[64*72], AL[64*72];
  __shared__ unsigned short BH[128*72], BL[128*72];
  const int tid = threadIdx.x;
  const int wave = tid>>6, lane = tid&63, l15 = lane&15, lq = lane>>4;
  const int m0 = blockIdx.x*64;
  const int b = m0>>15, nn = m0 & 32767;
  f32x4 acc[16] = {};

  for (int hh=0; hh<8; hh++){
    const int bhh = b*8 + hh;
    __syncthreads();
    {
      const int g = tid>>2, mq = (tid&3)*16;
      const unsigned* src = swT + ((size_t)bhh*64 + g)*NSEQ + nn + mq;
      #pragma unroll
      for (int i=0;i<4;i++){
        uint4 pv = *(const uint4*)(src + i*4);
        unsigned u[4]={pv.x,pv.y,pv.z,pv.w};
        #pragma unroll
        for (int j=0;j<4;j++){
          int m = mq + i*4 + j;
          AH[m*72+g] = (unsigned short)(u[j] & 0xFFFFu);
          AL[m*72+g] = (unsigned short)(u[j] >> 16);
        }
      }
    }
    #pragma unroll
    for (int chalf=0; chalf<2; chalf++){
      {
        const int c = tid>>1, gq = (tid&1)*32;
        const unsigned* bsrc = MtP + (size_t)bhh*16384 + (size_t)(chalf*128 + c)*64 + gq;
        #pragma unroll
        for (int i=0;i<8;i++){
          uint4 pv = *(const uint4*)(bsrc + i*4);
          ushort4 hh4, ll4;
          hh4.x=(unsigned short)(pv.x&0xFFFFu); ll4.x=(unsigned short)(pv.x>>16);
          hh4.y=(unsigned short)(pv.y&0xFFFFu); ll4.y=(unsigned short)(pv.y>>16);
          hh4.z=(unsigned short)(pv.z&0xFFFFu); ll4.z=(unsigned short)(pv.z>>16);
          hh4.w=(unsigned short)(pv.w&0xFFFFu); ll4.w=(unsigned short)(pv.w>>16);
          *(ushort4*)&BH[c*72 + gq + i*4] = hh4;
          *(ushort4*)&BL[c*72 + gq + i*4] = ll4;
        }
      }
      __syncthreads();
      #pragma unroll
      for (int ks=0; ks<2; ks++){
        const int koff = ks*32 + lq*8;
        short8v aH = *(const short8v*)&AH[(wave*16+l15)*72 + koff];
        short8v aL = *(const short8v*)&AL[(wave*16+l15)*72 + koff];
        #pragma unroll
        for (int ct=0; ct<8; ct++){
          short8v bH = *(const short8v*)&BH[(ct*16+l15)*72 + koff];
          short8v bL = *(const short8v*)&BL[(ct*16+l15)*72 + koff];
          acc[chalf*8+ct] = MFMA16(aH,bH,acc[chalf*8+ct],0,0,0);
          acc[chalf*8+ct] = MFMA16(aH,bL,acc[chalf*8+ct],0,0,0);
          acc[chalf*8+ct] = MFMA16(aL,bH,acc[chalf*8+ct],0,0,0);
        }
      }
      __syncthreads();
    }
  }
  #pragma unroll
  for (int ci=0; ci<16; ci++)
    #pragma unroll
    for (int r=0;r<4;r++){
      int c = (ci>>3)*128 + (ci&7)*16 + l15;
      out[(size_t)(m0 + wave*16 + lq*4 + r)*256 + c] = acc[ci][r] + bo[c];
    }
}

// ---------------------------------------------------------------------------
extern "C" void kernel_launch(void* const* d_in, const int* in_sizes, int n_in,
                              void* d_out, int out_size, void* d_ws, size_t ws_size,
                              hipStream_t stream) {
  (void)in_sizes; (void)n_in; (void)out_size;
  const float* x    = (const float*)d_in[0];
  const float* pos  = (const float*)d_in[1];
  const float* gum  = (const float*)d_in[2];
  const float* Wx   = (const float*)d_in[3];
  const float* bx   = (const float*)d_in[4];
  const float* W1   = (const float*)d_in[5];
  const float* b1   = (const float*)d_in[6];
  const float* W2   = (const float*)d_in[7];
  const float* b2   = (const float*)d_in[8];
  const float* bias = (const float*)d_in[9];
  const float* Wr   = (const float*)d_in[10];
  const float* br   = (const float*)d_in[11];
  const float* Ws   = (const float*)d_in[12];
  const float* bs   = (const float*)d_in[13];
  const float* Wq   = (const float*)d_in[14];
  const float* Wk   = (const float*)d_in[15];
  const float* Wv   = (const float*)d_in[16];
  const float* Wg1  = (const float*)d_in[17];
  const float* bg1  = (const float*)d_in[18];
  const float* Wg2  = (const float*)d_in[19];
  const float* bg2  = (const float*)d_in[20];
  const float* Wo   = (const float*)d_in[21];
  const float* bo   = (const float*)d_in[22];
  float* out = (float*)d_out;

  float*    xmid  = (float*)d_ws;
  unsigned* swT   = (unsigned*)(xmid + (size_t)33554432);
  float*    partp = (float*)(swT + (size_t)33554432);
  float*    stred = partp + (size_t)4259840;
  unsigned short* WxTH = (unsigned short*)(stred + (size_t)66560);
  unsigned short* WxTL  = WxTH + (size_t)131072;
  unsigned short* WqTH  = WxTL + (size_t)131072;
  unsigned short* WqTL  = WqTH + 4096;
  unsigned short* WkTH  = WqTL + 4096;
  unsigned short* WkTL  = WkTH + 4096;
  unsigned short* WvTH  = WkTL + 4096;
  unsigned short* WvTL  = WvTH + 4096;
  unsigned short* Wg1TH = WvTL + 4096;
  unsigned short* Wg1TL = Wg1TH + 8192;
  unsigned short* Wg2TH = Wg1TL + 8192;
  unsigned short* Wg2TL = Wg2TH + 4096;
  unsigned short* WoTH  = Wg2TL + 4096;
  unsigned short* WoTL  = WoTH + (size_t)131072;
  unsigned short* W1TH  = WoTL + (size_t)131072;
  unsigned short* W1TL  = W1TH + 4096;
  unsigned short* WsTH  = W1TL + 4096;
  unsigned short* WsTL  = WsTH + 4096;
  unsigned* MtP = (unsigned*)partp;  // alias: part dead after k3a
  const size_t need = ((size_t)33554432*2 + 4259840 + 66560)*4 + (size_t)589824*2;
  if (ws_size < need) return;

  k0_prep<<<512, 256, 0, stream>>>(Wx, WxTH, WxTL);
  k0b_prep<<<11, 256, 0, stream>>>(Wq, Wk, Wv, Wg1, Wg2, Wo, W1, Ws,
      WqTH,WqTL,WkTH,WkTL,WvTH,WvTL,Wg1TH,Wg1TL,Wg2TH,Wg2TL,WoTH,WoTL,W1TH,W1TL,WsTH,WsTL);
  k1_gemm_rope<<<1024, 256, 0, stream>>>(x, pos, WxTH, WxTL, bx, Wr, br, xmid);
  k2_tile<<<dim3(64,16), 256, 0, stream>>>(xmid, gum, W1TH, W1TL, b1, W2, b2, bias, WsTH, WsTL, bs, swT, partp);
  k3a_reduce<<<dim3(16,17), 256, 0, stream>>>(partp, stred);
  k3b_slice<<<16, 256, 0, stream>>>(stred, WqTH,WqTL,WkTH,WkTL,WvTH,WvTL,
      Wg1TH,Wg1TL,Wg2TH,Wg2TL,WoTH,WoTL, bg1, bg2, MtP);
  k4_out<<<1024, 256, 0, stream>>>(swT, MtP, bo, out);
}